// Round 11
// baseline (90.433 us; speedup 1.0000x reference)
//
#include <hip/hip_runtime.h>
#include <hip/hip_bf16.h>

typedef __attribute__((ext_vector_type(8))) short short8;
typedef __attribute__((ext_vector_type(4))) float f32x4;
typedef __attribute__((ext_vector_type(4))) unsigned uint4v;

#define LOG2E 1.4426950408889634f
#define ILN2SQ 0.4804530139182014f   // (ln2)^2, compensates LOG2E^2 in relu^2 path

// compiler emits v_cvt_pk_bf16_f32 for this (m240: do NOT hand-write the asm)
__device__ __forceinline__ unsigned packbf2(float a, float b) {
  __hip_bfloat162 h = __float22bfloat162_rn(make_float2(a, b));
  return *reinterpret_cast<unsigned*>(&h);
}
// XOR swizzle spreading 16B chunks across banks; bits 4..6 only (within 128B row)
__device__ __forceinline__ int swz(int row) {
  return ((row & 7) << 4) ^ (((row >> 3) & 3) << 5);
}
__device__ __forceinline__ void gload16(const void* g, void* l) {
  __builtin_amdgcn_global_load_lds(
      (const __attribute__((address_space(1))) unsigned int*)g,
      (__attribute__((address_space(3))) unsigned int*)l, 16, 0, 0);
}

// PV key permutation: logical slot p (0..63) within a V^T row maps to physical key
//   R = p>>5, g = (p&31)>>3, jj = p&7  ->  key = (R*2 + (jj>>2))*16 + g*4 + (jj&3)
// so that lane-group g's 16B fragment read delivers keys matching the lane's own
// QK^T accumulator scores (B-frag = concat of packed acc, no shuffles).
__device__ __forceinline__ int pv_key(int p) {
  const int R = p >> 5, g = (p & 31) >> 3, jj = p & 7;
  return (R * 2 + (jj >> 2)) * 16 + g * 4 + (jj & 3);
}

// ---------------- prep: fp32 -> bf16, pre-swizzled global layouts ----------------
// KP  = ws[0..8MB):   [bh][s][128B]      bf16 K rows, 16B chunks XOR-swz by s
// VTP = ws[8MB..16MB): [bh][t][e][128B]  bf16 V^T tiles, PV-KEY-PERMUTED within row
//        (byte pos 2*p holds V[pv_key(p)][e]); XOR-swz by e.
__global__ __launch_bounds__(256) void assa_prep(
    const float* __restrict__ K, const float* __restrict__ V, char* __restrict__ WS)
{
  constexpr int L = 2048, RS = 1024, E = 64;
  char* KP = WS;
  char* VTP = WS + (size_t)8 * 1024 * 1024;
  __shared__ float tile[64][65];
  const int tid = threadIdx.x;

  if (blockIdx.x < 1024) {
    // ---- K path: thread = quarter row (16 floats) ----
    const int gid = blockIdx.x * 256 + tid;
    const int rid = gid >> 2;            // bh*2048 + s
    const int e0 = (gid & 3) * 16;
    const int bh = rid >> 11, s = rid & 2047;
    const int b = bh >> 4, h = bh & 15;
    const float* kr = K + ((size_t)b * L + s) * RS + h * E + e0;
    const float4 u0 = *(const float4*)(kr);
    const float4 u1 = *(const float4*)(kr + 4);
    const float4 u2 = *(const float4*)(kr + 8);
    const float4 u3 = *(const float4*)(kr + 12);
    uint4v w0, w1;
    w0[0] = packbf2(u0.x, u0.y); w0[1] = packbf2(u0.z, u0.w);
    w0[2] = packbf2(u1.x, u1.y); w0[3] = packbf2(u1.z, u1.w);
    w1[0] = packbf2(u2.x, u2.y); w1[1] = packbf2(u2.z, u2.w);
    w1[2] = packbf2(u3.x, u3.y); w1[3] = packbf2(u3.z, u3.w);
    char* dst = KP + (size_t)rid * 128;
    const int sz = swz(s);
    *(uint4v*)(dst + ((e0 * 2) ^ sz)) = w0;
    *(uint4v*)(dst + ((e0 * 2 + 16) ^ sz)) = w1;
  } else {
    // ---- V path: block = (bh, t); transpose 64x64 via LDS, pv_key-permuted write ----
    const int bx = blockIdx.x - 1024;
    const int bh = bx >> 5, t5 = bx & 31;
    const int b = bh >> 4, h = bh & 15;
    const float* vb = V + ((size_t)b * L + t5 * 64) * RS + h * E;
    {
      const int key = tid >> 2, e0 = (tid & 3) * 16;
      const float* vr = vb + (size_t)key * RS + e0;
      const float4 u0 = *(const float4*)(vr);
      const float4 u1 = *(const float4*)(vr + 4);
      const float4 u2 = *(const float4*)(vr + 8);
      const float4 u3 = *(const float4*)(vr + 12);
      float* tr = &tile[key][e0];
      tr[0] = u0.x; tr[1] = u0.y; tr[2] = u0.z; tr[3] = u0.w;
      tr[4] = u1.x; tr[5] = u1.y; tr[6] = u1.z; tr[7] = u1.w;
      tr[8] = u2.x; tr[9] = u2.y; tr[10] = u2.z; tr[11] = u2.w;
      tr[12] = u3.x; tr[13] = u3.y; tr[14] = u3.z; tr[15] = u3.w;
    }
    __syncthreads();
    const int e = tid >> 2, p0 = (tid & 3) * 16;   // positions p0..p0+15
    uint4v w0, w1;
    #pragma unroll
    for (int i = 0; i < 4; ++i)
      w0[i] = packbf2(tile[pv_key(p0 + 2 * i)][e], tile[pv_key(p0 + 2 * i + 1)][e]);
    #pragma unroll
    for (int i = 0; i < 4; ++i)
      w1[i] = packbf2(tile[pv_key(p0 + 8 + 2 * i)][e], tile[pv_key(p0 + 9 + 2 * i)][e]);
    char* dst = VTP + ((size_t)bx * 64 + e) * 128;
    const int sz = swz(e);
    *(uint4v*)(dst + ((p0 * 2) ^ sz)) = w0;
    *(uint4v*)(dst + ((p0 * 2 + 16) ^ sz)) = w1;
  }
}

// -------- main fused: QBLK=128, 8 waves x 16 q-rows, KVBLK=128 (2 subtiles) --------
__global__ __launch_bounds__(512, 4) void assa_fused(
    const float* __restrict__ Q, const char* __restrict__ WS,
    const float* __restrict__ A1, const float* __restrict__ A2,
    float* __restrict__ O)
{
  constexpr int L = 2048, H = 16, E = 64, RS = H * E;

  __shared__ __align__(16) char Kb[2 * 16384];   // K region double buffer (128 keys)
  __shared__ __align__(16) char Vb[2 * 16384];   // V^T region double buffer

  const int t = threadIdx.x;
  const int wv = t >> 6;        // wave 0..7
  const int lane = t & 63;
  const int g = lane >> 4;
  const int c = lane & 15;

  const int bh = blockIdx.x;            // x = bh -> XCD-pinned K/V reuse
  const int q0 = blockIdx.y * 128;
  const int b = bh >> 4;
  const int h = bh & 15;

  const float* qb = Q + (size_t)b * L * RS + (size_t)h * E;
  float* ob = O + (size_t)b * L * RS + (size_t)h * E;
  const char* KP = WS;
  const char* VTP = WS + (size_t)8 * 1024 * 1024;

  const float a1 = A1[0], a2 = A2[0];
  const float am = fmaxf(a1, a2);
  const float e1 = expf(a1 - am), e2 = expf(a2 - am);
  const float alpha1 = (e1 / (e1 + e2)) * ILN2SQ;  // relu^2 path: undo LOG2E^2
  const float alpha2 = e2 / (e1 + e2);

  // This wave's 16 q-rows: q0 + wv*16 + c.
  // B-frag layout: lane holds Q[q][e = ks*32 + g*8 + j], pre-scaled by 0.125*LOG2E.
  short8 aq[2];
  {
    const float qs = 0.125f * LOG2E;
    const float* qr = qb + (size_t)(q0 + wv * 16 + c) * RS;
    #pragma unroll
    for (int ks = 0; ks < 2; ++ks) {
      const float4 u0 = *(const float4*)(qr + ks * 32 + g * 8);
      const float4 u1 = *(const float4*)(qr + ks * 32 + g * 8 + 4);
      union { unsigned u[4]; short8 s; } f;
      f.u[0] = packbf2(u0.x * qs, u0.y * qs);
      f.u[1] = packbf2(u0.z * qs, u0.w * qs);
      f.u[2] = packbf2(u1.x * qs, u1.y * qs);
      f.u[3] = packbf2(u1.z * qs, u1.w * qs);
      aq[ks] = f.s;
    }
  }

  // precomputed swizzled LDS byte offsets (within one 8KB subtile)
  int ka[8];   // K frag reads: [kt][ks]
  #pragma unroll
  for (int kt = 0; kt < 4; ++kt) {
    const int row = kt * 16 + c;
    const int s = swz(row);
    ka[kt * 2 + 0] = (row * 128 + g * 16) ^ s;
    ka[kt * 2 + 1] = (row * 128 + 64 + g * 16) ^ s;
  }
  int va[8];   // V^T frag reads: [et][tp]  (tp0 = keys kt0/kt1, tp1 = keys kt2/kt3)
  #pragma unroll
  for (int et = 0; et < 4; ++et) {
    const int row = et * 16 + c;
    const int s = swz(row);
    va[et * 2 + 0] = (row * 128 + g * 16) ^ s;
    va[et * 2 + 1] = (row * 128 + 64 + g * 16) ^ s;
  }

  const f32x4 zero4 = {0.0f, 0.0f, 0.0f, 0.0f};
  f32x4 od[4], os[4];
  #pragma unroll
  for (int i = 0; i < 4; ++i) { od[i] = zero4; os[i] = zero4; }
  float psum = 0.0f;

  // staging: 512 threads x 16B = 8KB per gload pass; region = 16KB each for K and V
  const char* kp = KP + (size_t)bh * (2048 * 128) + t * 16;
  const char* vp = VTP + (size_t)bh * (2048 * 128) + t * 16;
  char* kd = Kb + wv * 1024;   // wave-uniform base (lane*16 added by HW)
  char* vd = Vb + wv * 1024;

  union U8 { unsigned u[4]; short8 s; };

#define STAGE(TOFF, HALF)                                \
  do {                                                   \
    gload16(kp + (TOFF), kd + (HALF));                   \
    gload16(kp + (TOFF) + 8192, kd + (HALF) + 8192);     \
    gload16(vp + (TOFF), vd + (HALF));                   \
    gload16(vp + (TOFF) + 8192, vd + (HALF) + 8192);     \
  } while (0)

#define QKPART(ACC, OFS)                                                             \
  do {                                                                               \
    _Pragma("unroll")                                                                \
    for (int kt = 0; kt < 4; ++kt) {                                                 \
      const short8 kf0 = *(const short8*)(Kb + ka[kt * 2 + 0] + (OFS));              \
      const short8 kf1 = *(const short8*)(Kb + ka[kt * 2 + 1] + (OFS));              \
      ACC[kt] = __builtin_amdgcn_mfma_f32_16x16x32_bf16(kf0, aq[0], ACC[kt], 0, 0, 0);\
      ACC[kt] = __builtin_amdgcn_mfma_f32_16x16x32_bf16(kf1, aq[1], ACC[kt], 0, 0, 0);\
    }                                                                                \
  } while (0)

#define SMPV(ACC, OFS)                                                               \
  do {                                                                               \
    short8 vfr0[4], vfr1[4];                                                         \
    _Pragma("unroll")                                                                \
    for (int et = 0; et < 4; ++et) {                                                 \
      vfr0[et] = *(const short8*)(Vb + va[et * 2 + 0] + (OFS));                      \
      vfr1[et] = *(const short8*)(Vb + va[et * 2 + 1] + (OFS));                      \
    }                                                                                \
    unsigned pdw[8], psw[8];                                                         \
    _Pragma("unroll")                                                                \
    for (int kt = 0; kt < 4; ++kt) {                                                 \
      const float x0 = __builtin_amdgcn_exp2f(ACC[kt][0]);                           \
      const float x1 = __builtin_amdgcn_exp2f(ACC[kt][1]);                           \
      const float x2 = __builtin_amdgcn_exp2f(ACC[kt][2]);                           \
      const float x3 = __builtin_amdgcn_exp2f(ACC[kt][3]);                           \
      psum += (x0 + x1) + (x2 + x3);                                                 \
      const float r0 = fmaxf(ACC[kt][0], 0.0f), r1 = fmaxf(ACC[kt][1], 0.0f);        \
      const float r2 = fmaxf(ACC[kt][2], 0.0f), r3 = fmaxf(ACC[kt][3], 0.0f);        \
      pdw[kt * 2 + 0] = packbf2(x0, x1);                                             \
      pdw[kt * 2 + 1] = packbf2(x2, x3);                                             \
      psw[kt * 2 + 0] = packbf2(r0 * r0, r1 * r1);                                   \
      psw[kt * 2 + 1] = packbf2(r2 * r2, r3 * r3);                                   \
    }                                                                                \
    __builtin_amdgcn_s_setprio(1);                                                   \
    _Pragma("unroll")                                                                \
    for (int tp = 0; tp < 2; ++tp) {                                                 \
      U8 bpd, bps;                                                                   \
      bpd.u[0] = pdw[tp * 4 + 0]; bpd.u[1] = pdw[tp * 4 + 1];                        \
      bpd.u[2] = pdw[tp * 4 + 2]; bpd.u[3] = pdw[tp * 4 + 3];                        \
      bps.u[0] = psw[tp * 4 + 0]; bps.u[1] = psw[tp * 4 + 1];                        \
      bps.u[2] = psw[tp * 4 + 2]; bps.u[3] = psw[tp * 4 + 3];                        \
      _Pragma("unroll")                                                              \
      for (int et = 0; et < 4; ++et) {                                               \
        const short8 vf = tp ? vfr1[et] : vfr0[et];                                  \
        od[et] = __builtin_amdgcn_mfma_f32_16x16x32_bf16(vf, bpd.s, od[et], 0, 0, 0);\
        os[et] = __builtin_amdgcn_mfma_f32_16x16x32_bf16(vf, bps.s, os[et], 0, 0, 0);\
      }                                                                              \
    }                                                                                \
    __builtin_amdgcn_s_setprio(0);                                                   \
  } while (0)

  STAGE(0, 0);
  __syncthreads();
  size_t toff = 16384;
  for (int r = 0; r < 16; ++r) {
    if (r + 1 < 16) { STAGE(toff, ((r + 1) & 1) * 16384); toff += 16384; }
    const int OFS = (r & 1) * 16384;
    // region: QK(s0), QK(s1) first; SM(s0) VALU overlaps QK(s1)/PV MFMA via scheduler
    f32x4 acc0[4], acc1[4];
    #pragma unroll
    for (int i = 0; i < 4; ++i) { acc0[i] = zero4; acc1[i] = zero4; }
    QKPART(acc0, OFS);
    QKPART(acc1, OFS + 8192);
    SMPV(acc0, OFS);
    SMPV(acc1, OFS + 8192);
    __syncthreads();
  }
#undef STAGE
#undef QKPART
#undef SMPV

  // ---- final l reduction (per q-row = c, across 4 lane groups) ----
  float l = psum;
  l += __shfl_xor(l, 16);
  l += __shfl_xor(l, 32);

  // ---- epilogue: out[q][e=et*16+g*4+r] ----
  const float wd = alpha2 / l;
  float* orow = ob + (size_t)(q0 + wv * 16 + c) * RS;
  #pragma unroll
  for (int et = 0; et < 4; ++et) {
    float4 o;
    o.x = alpha1 * os[et][0] + wd * od[et][0];
    o.y = alpha1 * os[et][1] + wd * od[et][1];
    o.z = alpha1 * os[et][2] + wd * od[et][2];
    o.w = alpha1 * os[et][3] + wd * od[et][3];
    *(float4*)(orow + et * 16 + g * 4) = o;
  }
}

extern "C" void kernel_launch(void* const* d_in, const int* in_sizes, int n_in,
                              void* d_out, int out_size, void* d_ws, size_t ws_size,
                              hipStream_t stream) {
  const float* q = (const float*)d_in[0];
  const float* k = (const float*)d_in[1];
  const float* v = (const float*)d_in[2];
  const float* a1 = (const float*)d_in[3];
  const float* a2 = (const float*)d_in[4];
  float* out = (float*)d_out;
  char* ws = (char*)d_ws;

  assa_prep<<<2048, 256, 0, stream>>>(k, v, ws);
  dim3 grid(32, 16);  // x = bh (XCD-pinned), y = q-tile of 128 rows
  assa_fused<<<grid, 512, 0, stream>>>(q, ws, a1, a2, out);
}

// Round 13
// 78.962 us; speedup vs baseline: 1.1453x; 1.1453x over previous
//
#include <hip/hip_runtime.h>
#include <hip/hip_bf16.h>

typedef __attribute__((ext_vector_type(8))) short short8;
typedef __attribute__((ext_vector_type(4))) float f32x4;
typedef __attribute__((ext_vector_type(2))) float f32x2;
typedef __attribute__((ext_vector_type(4))) unsigned uint4v;

#define LOG2E 1.4426950408889634f
#define ILN2SQ 0.4804530139182014f   // (ln2)^2, compensates LOG2E^2 in relu^2 path

// compiler emits v_cvt_pk_bf16_f32 for this (m240: do NOT hand-write the asm)
__device__ __forceinline__ unsigned packbf2(float a, float b) {
  __hip_bfloat162 h = __float22bfloat162_rn(make_float2(a, b));
  return *reinterpret_cast<unsigned*>(&h);
}
// XOR swizzle spreading 16B chunks across banks; bits 4..6 only (within 128B row)
__device__ __forceinline__ int swz(int row) {
  return ((row & 7) << 4) ^ (((row >> 3) & 3) << 5);
}
__device__ __forceinline__ void gload16(const void* g, void* l) {
  __builtin_amdgcn_global_load_lds(
      (const __attribute__((address_space(1))) unsigned int*)g,
      (__attribute__((address_space(3))) unsigned int*)l, 16, 0, 0);
}

// PV key permutation: logical slot p (0..63) within a V^T row maps to physical key
//   R = p>>5, g = (p&31)>>3, jj = p&7  ->  key = (R*2 + (jj>>2))*16 + g*4 + (jj&3)
// so that lane-group g's 16B fragment read delivers keys matching the lane's own
// QK^T accumulator scores (B-frag = concat of packed acc, no shuffles).
__device__ __forceinline__ int pv_key(int p) {
  const int R = p >> 5, g = (p & 31) >> 3, jj = p & 7;
  return (R * 2 + (jj >> 2)) * 16 + g * 4 + (jj & 3);
}

// ---------------- prep: fp32 -> bf16, pre-swizzled global layouts ----------------
// KP  = ws[0..8MB):   [bh][s][128B]      bf16 K rows, 16B chunks XOR-swz by s
// VTP = ws[8MB..16MB): [bh][t][e][128B]  bf16 V^T tiles, PV-KEY-PERMUTED within row
//        (byte pos 2*p holds V[pv_key(p)][e]); XOR-swz by e.
__global__ __launch_bounds__(256) void assa_prep(
    const float* __restrict__ K, const float* __restrict__ V, char* __restrict__ WS)
{
  constexpr int L = 2048, RS = 1024, E = 64;
  char* KP = WS;
  char* VTP = WS + (size_t)8 * 1024 * 1024;
  __shared__ float tile[64][65];
  const int tid = threadIdx.x;

  if (blockIdx.x < 1024) {
    // ---- K path: thread = quarter row (16 floats) ----
    const int gid = blockIdx.x * 256 + tid;
    const int rid = gid >> 2;            // bh*2048 + s
    const int e0 = (gid & 3) * 16;
    const int bh = rid >> 11, s = rid & 2047;
    const int b = bh >> 4, h = bh & 15;
    const float* kr = K + ((size_t)b * L + s) * RS + h * E + e0;
    const float4 u0 = *(const float4*)(kr);
    const float4 u1 = *(const float4*)(kr + 4);
    const float4 u2 = *(const float4*)(kr + 8);
    const float4 u3 = *(const float4*)(kr + 12);
    uint4v w0, w1;
    w0[0] = packbf2(u0.x, u0.y); w0[1] = packbf2(u0.z, u0.w);
    w0[2] = packbf2(u1.x, u1.y); w0[3] = packbf2(u1.z, u1.w);
    w1[0] = packbf2(u2.x, u2.y); w1[1] = packbf2(u2.z, u2.w);
    w1[2] = packbf2(u3.x, u3.y); w1[3] = packbf2(u3.z, u3.w);
    char* dst = KP + (size_t)rid * 128;
    const int sz = swz(s);
    *(uint4v*)(dst + ((e0 * 2) ^ sz)) = w0;
    *(uint4v*)(dst + ((e0 * 2 + 16) ^ sz)) = w1;
  } else {
    // ---- V path: block = (bh, t); transpose 64x64 via LDS, pv_key-permuted write ----
    const int bx = blockIdx.x - 1024;
    const int bh = bx >> 5, t5 = bx & 31;
    const int b = bh >> 4, h = bh & 15;
    const float* vb = V + ((size_t)b * L + t5 * 64) * RS + h * E;
    {
      const int key = tid >> 2, e0 = (tid & 3) * 16;
      const float* vr = vb + (size_t)key * RS + e0;
      const float4 u0 = *(const float4*)(vr);
      const float4 u1 = *(const float4*)(vr + 4);
      const float4 u2 = *(const float4*)(vr + 8);
      const float4 u3 = *(const float4*)(vr + 12);
      float* tr = &tile[key][e0];
      tr[0] = u0.x; tr[1] = u0.y; tr[2] = u0.z; tr[3] = u0.w;
      tr[4] = u1.x; tr[5] = u1.y; tr[6] = u1.z; tr[7] = u1.w;
      tr[8] = u2.x; tr[9] = u2.y; tr[10] = u2.z; tr[11] = u2.w;
      tr[12] = u3.x; tr[13] = u3.y; tr[14] = u3.z; tr[15] = u3.w;
    }
    __syncthreads();
    const int e = tid >> 2, p0 = (tid & 3) * 16;   // positions p0..p0+15
    uint4v w0, w1;
    #pragma unroll
    for (int i = 0; i < 4; ++i)
      w0[i] = packbf2(tile[pv_key(p0 + 2 * i)][e], tile[pv_key(p0 + 2 * i + 1)][e]);
    #pragma unroll
    for (int i = 0; i < 4; ++i)
      w1[i] = packbf2(tile[pv_key(p0 + 8 + 2 * i)][e], tile[pv_key(p0 + 9 + 2 * i)][e]);
    char* dst = VTP + ((size_t)bx * 64 + e) * 128;
    const int sz = swz(e);
    *(uint4v*)(dst + ((p0 * 2) ^ sz)) = w0;
    *(uint4v*)(dst + ((p0 * 2 + 16) ^ sz)) = w1;
  }
}

// -------- main fused: QBLK=128, 8 waves x 16 q-rows, KVBLK=128 (2 subtiles) --------
__global__ __launch_bounds__(512, 4) void assa_fused(
    const float* __restrict__ Q, const char* __restrict__ WS,
    const float* __restrict__ A1, const float* __restrict__ A2,
    float* __restrict__ O)
{
  constexpr int L = 2048, H = 16, E = 64, RS = H * E;

  __shared__ __align__(16) char Kb[2 * 16384];   // K region double buffer (128 keys)
  __shared__ __align__(16) char Vb[2 * 16384];   // V^T region double buffer

  const int t = threadIdx.x;
  const int wv = t >> 6;        // wave 0..7
  const int lane = t & 63;
  const int g = lane >> 4;
  const int c = lane & 15;

  const int bh = blockIdx.x;            // x = bh -> XCD-pinned K/V reuse
  const int q0 = blockIdx.y * 128;
  const int b = bh >> 4;
  const int h = bh & 15;

  const float* qb = Q + (size_t)b * L * RS + (size_t)h * E;
  float* ob = O + (size_t)b * L * RS + (size_t)h * E;
  const char* KP = WS;
  const char* VTP = WS + (size_t)8 * 1024 * 1024;

  const float a1 = A1[0], a2 = A2[0];
  const float am = fmaxf(a1, a2);
  const float e1 = expf(a1 - am), e2 = expf(a2 - am);
  const float alpha1 = (e1 / (e1 + e2)) * ILN2SQ;  // relu^2 path: undo LOG2E^2
  const float alpha2 = e2 / (e1 + e2);

  // This wave's 16 q-rows: q0 + wv*16 + c.
  // B-frag layout: lane holds Q[q][e = ks*32 + g*8 + j], pre-scaled by 0.125*LOG2E.
  short8 aq[2];
  {
    const float qs = 0.125f * LOG2E;
    const float* qr = qb + (size_t)(q0 + wv * 16 + c) * RS;
    #pragma unroll
    for (int ks = 0; ks < 2; ++ks) {
      const float4 u0 = *(const float4*)(qr + ks * 32 + g * 8);
      const float4 u1 = *(const float4*)(qr + ks * 32 + g * 8 + 4);
      union { unsigned u[4]; short8 s; } f;
      f.u[0] = packbf2(u0.x * qs, u0.y * qs);
      f.u[1] = packbf2(u0.z * qs, u0.w * qs);
      f.u[2] = packbf2(u1.x * qs, u1.y * qs);
      f.u[3] = packbf2(u1.z * qs, u1.w * qs);
      aq[ks] = f.s;
    }
  }

  // precomputed swizzled LDS byte offsets (within one 8KB subtile).
  // NOTE: K-frag and V-frag offset arrays are provably identical (same formula
  // with kt<->et, ks<->tp), so ONE array serves both (saves 8 VGPRs).
  int ka[8];   // [i16][half]: row = i16*16+c; half = 0 -> +0, 1 -> +64
  #pragma unroll
  for (int i16 = 0; i16 < 4; ++i16) {
    const int row = i16 * 16 + c;
    const int s = swz(row);
    ka[i16 * 2 + 0] = (row * 128 + g * 16) ^ s;
    ka[i16 * 2 + 1] = (row * 128 + 64 + g * 16) ^ s;
  }

  const f32x4 zero4 = {0.0f, 0.0f, 0.0f, 0.0f};
  f32x4 od[4], os[4];
  #pragma unroll
  for (int i = 0; i < 4; ++i) { od[i] = zero4; os[i] = zero4; }
  f32x2 psa = {0.0f, 0.0f}, psb = {0.0f, 0.0f};

  // staging: 512 threads x 16B = 8KB per gload pass; region = 16KB each for K and V
  const char* kp = KP + (size_t)bh * (2048 * 128) + t * 16;
  const char* vp = VTP + (size_t)bh * (2048 * 128) + t * 16;
  char* kd = Kb + wv * 1024;   // wave-uniform base (lane*16 added by HW)
  char* vd = Vb + wv * 1024;

  union U8 { unsigned u[4]; short8 s; };

#define STAGE(TOFF, HALF)                                \
  do {                                                   \
    gload16(kp + (TOFF), kd + (HALF));                   \
    gload16(kp + (TOFF) + 8192, kd + (HALF) + 8192);     \
    gload16(vp + (TOFF), vd + (HALF));                   \
    gload16(vp + (TOFF) + 8192, vd + (HALF) + 8192);     \
  } while (0)

#define QKPART(ACC, OFS)                                                             \
  do {                                                                               \
    _Pragma("unroll")                                                                \
    for (int kt = 0; kt < 4; ++kt) {                                                 \
      const short8 kf0 = *(const short8*)(Kb + ka[kt * 2 + 0] + (OFS));              \
      const short8 kf1 = *(const short8*)(Kb + ka[kt * 2 + 1] + (OFS));              \
      ACC[kt] = __builtin_amdgcn_mfma_f32_16x16x32_bf16(kf0, aq[0], ACC[kt], 0, 0, 0);\
      ACC[kt] = __builtin_amdgcn_mfma_f32_16x16x32_bf16(kf1, aq[1], ACC[kt], 0, 0, 0);\
    }                                                                                \
  } while (0)

// per-tp slim softmax+PV: 4 V-frag loads (16 VGPR), pk-math SM, 8 MFMAs.
#define SMPV(ACC, OFS)                                                               \
  do {                                                                               \
    _Pragma("unroll")                                                                \
    for (int tp = 0; tp < 2; ++tp) {                                                 \
      short8 vfA0 = *(const short8*)(Vb + ka[0 * 2 + tp] + (OFS));                   \
      short8 vfA1 = *(const short8*)(Vb + ka[1 * 2 + tp] + (OFS));                   \
      short8 vfA2 = *(const short8*)(Vb + ka[2 * 2 + tp] + (OFS));                   \
      short8 vfA3 = *(const short8*)(Vb + ka[3 * 2 + tp] + (OFS));                   \
      const f32x4 a0 = ACC[tp * 2], a1 = ACC[tp * 2 + 1];                            \
      const float x00 = __builtin_amdgcn_exp2f(a0[0]);                               \
      const float x01 = __builtin_amdgcn_exp2f(a0[1]);                               \
      const float x02 = __builtin_amdgcn_exp2f(a0[2]);                               \
      const float x03 = __builtin_amdgcn_exp2f(a0[3]);                               \
      const float x10 = __builtin_amdgcn_exp2f(a1[0]);                               \
      const float x11 = __builtin_amdgcn_exp2f(a1[1]);                               \
      const float x12 = __builtin_amdgcn_exp2f(a1[2]);                               \
      const float x13 = __builtin_amdgcn_exp2f(a1[3]);                               \
      psa += (f32x2){x00, x01}; psb += (f32x2){x02, x03};                            \
      psa += (f32x2){x10, x11}; psb += (f32x2){x12, x13};                            \
      f32x2 r00 = {a0[0], a0[1]}, r01 = {a0[2], a0[3]};                              \
      f32x2 r10 = {a1[0], a1[1]}, r11 = {a1[2], a1[3]};                              \
      const f32x2 z2 = {0.0f, 0.0f};                                                 \
      r00 = __builtin_elementwise_max(r00, z2); r00 *= r00;                          \
      r01 = __builtin_elementwise_max(r01, z2); r01 *= r01;                          \
      r10 = __builtin_elementwise_max(r10, z2); r10 *= r10;                          \
      r11 = __builtin_elementwise_max(r11, z2); r11 *= r11;                          \
      U8 bpd, bps;                                                                   \
      bpd.u[0] = packbf2(x00, x01); bpd.u[1] = packbf2(x02, x03);                    \
      bpd.u[2] = packbf2(x10, x11); bpd.u[3] = packbf2(x12, x13);                    \
      bps.u[0] = packbf2(r00[0], r00[1]); bps.u[1] = packbf2(r01[0], r01[1]);        \
      bps.u[2] = packbf2(r10[0], r10[1]); bps.u[3] = packbf2(r11[0], r11[1]);        \
      __builtin_amdgcn_s_setprio(1);                                                 \
      od[0] = __builtin_amdgcn_mfma_f32_16x16x32_bf16(vfA0, bpd.s, od[0], 0, 0, 0);  \
      os[0] = __builtin_amdgcn_mfma_f32_16x16x32_bf16(vfA0, bps.s, os[0], 0, 0, 0);  \
      od[1] = __builtin_amdgcn_mfma_f32_16x16x32_bf16(vfA1, bpd.s, od[1], 0, 0, 0);  \
      os[1] = __builtin_amdgcn_mfma_f32_16x16x32_bf16(vfA1, bps.s, os[1], 0, 0, 0);  \
      od[2] = __builtin_amdgcn_mfma_f32_16x16x32_bf16(vfA2, bpd.s, od[2], 0, 0, 0);  \
      os[2] = __builtin_amdgcn_mfma_f32_16x16x32_bf16(vfA2, bps.s, os[2], 0, 0, 0);  \
      od[3] = __builtin_amdgcn_mfma_f32_16x16x32_bf16(vfA3, bpd.s, od[3], 0, 0, 0);  \
      os[3] = __builtin_amdgcn_mfma_f32_16x16x32_bf16(vfA3, bps.s, os[3], 0, 0, 0);  \
      __builtin_amdgcn_s_setprio(0);                                                 \
    }                                                                                \
  } while (0)

  STAGE(0, 0);
  __syncthreads();
  size_t toff = 16384;
  for (int r = 0; r < 16; ++r) {
    if (r + 1 < 16) { STAGE(toff, ((r + 1) & 1) * 16384); toff += 16384; }
    const int OFS = (r & 1) * 16384;
    // region: QK(s0), QK(s1) first; SM(s0) VALU overlaps QK(s1)/PV MFMA in-flight
    f32x4 acc0[4], acc1[4];
    #pragma unroll
    for (int i = 0; i < 4; ++i) { acc0[i] = zero4; acc1[i] = zero4; }
    QKPART(acc0, OFS);
    QKPART(acc1, OFS + 8192);
    SMPV(acc0, OFS);
    SMPV(acc1, OFS + 8192);
    __syncthreads();
  }
#undef STAGE
#undef QKPART
#undef SMPV

  // ---- final l reduction (per q-row = c, across 4 lane groups) ----
  const f32x2 lv = psa + psb;
  float l = lv[0] + lv[1];
  l += __shfl_xor(l, 16);
  l += __shfl_xor(l, 32);

  // ---- epilogue: out[q][e=et*16+g*4+r] ----
  const float wd = alpha2 / l;
  float* orow = ob + (size_t)(q0 + wv * 16 + c) * RS;
  #pragma unroll
  for (int et = 0; et < 4; ++et) {
    float4 o;
    o.x = alpha1 * os[et][0] + wd * od[et][0];
    o.y = alpha1 * os[et][1] + wd * od[et][1];
    o.z = alpha1 * os[et][2] + wd * od[et][2];
    o.w = alpha1 * os[et][3] + wd * od[et][3];
    *(float4*)(orow + et * 16 + g * 4) = o;
  }
}

extern "C" void kernel_launch(void* const* d_in, const int* in_sizes, int n_in,
                              void* d_out, int out_size, void* d_ws, size_t ws_size,
                              hipStream_t stream) {
  const float* q = (const float*)d_in[0];
  const float* k = (const float*)d_in[1];
  const float* v = (const float*)d_in[2];
  const float* a1 = (const float*)d_in[3];
  const float* a2 = (const float*)d_in[4];
  float* out = (float*)d_out;
  char* ws = (char*)d_ws;

  assa_prep<<<2048, 256, 0, stream>>>(k, v, ws);
  dim3 grid(32, 16);  // x = bh (XCD-pinned), y = q-tile of 128 rows
  assa_fused<<<grid, 512, 0, stream>>>(q, ws, a1, a2, out);
}